// Round 5
// baseline (19394.284 us; speedup 1.0000x reference)
//
#include <hip/hip_runtime.h>
#include <hip/hip_bf16.h>
#include <math.h>

// GREEN-ANCHOR: pure fp32 scalar pipeline. ALL tensors fp32 (inputs AND
// output), per the reference dtypes — the 4-round failure matrix showed
// outcome depends only on dtype assumptions (in=bf16 -> NaN; out=bf16 ->
// finite 3.03 garbage), and the harness's "(bf16, ...)" label is hard-coded.
// B=4, M=2048, D=1024. q=x@wq.T etc, RoPE(q,k), causal softmax(qk^T/32)@v.
// Workspace: q/k/v fp32 (24 MiB) + S fp32 (16 MiB) = 40 MiB, per-batch.

// One thread per output element. grid (4, 2048, 3): n-chunk, m, z(q/k/v).
// out[m][n] = sum_d x[m][d] * W[n][d]   (NT: both rows contiguous)
__global__ __launch_bounds__(256) void proj_kernel(
    const float* __restrict__ x,
    const float* __restrict__ wq, const float* __restrict__ wk,
    const float* __restrict__ wv,
    float* __restrict__ q, float* __restrict__ k, float* __restrict__ v)
{
    const int n = blockIdx.x * 256 + threadIdx.x;
    const int m = blockIdx.y;
    const int z = blockIdx.z;
    const float* W   = (z == 0) ? wq : (z == 1) ? wk : wv;
    float*      outp = (z == 0) ? q  : (z == 1) ? k  : v;
    const float4* xr = (const float4*)(x + (size_t)m * 1024);
    const float4* wr = (const float4*)(W + (size_t)n * 1024);
    float acc = 0.0f;
    for (int kk = 0; kk < 256; ++kk) {
        float4 a = xr[kk], b = wr[kk];
        acc += a.x * b.x + a.y * b.y + a.z * b.z + a.w * b.w;
    }
    outp[(size_t)m * 1024 + n] = acc;
}

// RoPE in place on q and k. One thread per (m, pair i).
// phi = 10000^(-2*(i-1)/1024)  [reference's (i-1.0) quirk], ang = m*phi.
// oe = te*c + to*s ; oo = -te*s + to*c   (te=elem 2i, to=elem 2i+1)
__global__ __launch_bounds__(256) void rope_kernel(
    float* __restrict__ q, float* __restrict__ k)
{
    const int idx = blockIdx.x * 256 + threadIdx.x;   // [0, 2048*512)
    const int m = idx >> 9, i = idx & 511;
    const float phi = powf(10000.0f, -2.0f * ((float)i - 1.0f) / 1024.0f);
    float ang = (float)m * phi;
    float s, c;
    sincosf(ang, &s, &c);
    float* qp = q + (size_t)m * 1024 + 2 * i;
    float te = qp[0], to = qp[1];
    qp[0] = te * c + to * s;
    qp[1] = -te * s + to * c;
    float* kp = k + (size_t)m * 1024 + 2 * i;
    te = kp[0]; to = kp[1];
    kp[0] = te * c + to * s;
    kp[1] = -te * s + to * c;
}

// S[m][n] = q_m . k_n / 32 for n <= m (upper triangle never written/read).
// grid (8, 2048): n-chunk, m.
__global__ __launch_bounds__(256) void scores_kernel(
    const float* __restrict__ q, const float* __restrict__ k,
    float* __restrict__ S)
{
    const int m = blockIdx.y;
    if ((int)(blockIdx.x * 256) > m) return;   // whole block above diagonal
    const int n = blockIdx.x * 256 + threadIdx.x;
    if (n > m) return;
    const float4* qr = (const float4*)(q + (size_t)m * 1024);
    const float4* kr = (const float4*)(k + (size_t)n * 1024);
    float acc = 0.0f;
    for (int kk = 0; kk < 256; ++kk) {
        float4 a = qr[kk], b = kr[kk];
        acc += a.x * b.x + a.y * b.y + a.z * b.z + a.w * b.w;
    }
    S[(size_t)m * 2048 + n] = acc * 0.03125f;   // 1/sqrt(1024)
}

// Row softmax in place over valid keys [0, row].
__global__ __launch_bounds__(256) void softmax_kernel(float* __restrict__ S)
{
    __shared__ float red[256];
    const int row = blockIdx.x, tid = threadIdx.x;
    float* s = S + (size_t)row * 2048;
    const int n = row + 1;

    float mx = -3.402823466e38f;
    for (int j = tid; j < n; j += 256) mx = fmaxf(mx, s[j]);
    red[tid] = mx; __syncthreads();
    for (int off = 128; off > 0; off >>= 1) {
        if (tid < off) red[tid] = fmaxf(red[tid], red[tid + off]);
        __syncthreads();
    }
    mx = red[0]; __syncthreads();

    float sum = 0.0f;
    for (int j = tid; j < n; j += 256) sum += expf(s[j] - mx);
    red[tid] = sum; __syncthreads();
    for (int off = 128; off > 0; off >>= 1) {
        if (tid < off) red[tid] += red[tid + off];
        __syncthreads();
    }
    const float inv = 1.0f / red[0];

    for (int j = tid; j < n; j += 256) s[j] = expf(s[j] - mx) * inv;
}

// out[m][:] = sum_{k<=m} P[m][k] * v[k][:].  Block per m; thread per 4 cols.
__global__ __launch_bounds__(256) void pv_kernel(
    const float* __restrict__ S, const float* __restrict__ v,
    float* __restrict__ out)
{
    const int m = blockIdx.x, tid = threadIdx.x;
    const float* srow = S + (size_t)m * 2048;
    const float4* vr = (const float4*)v;     // [2048][256] float4
    float4 acc = {0.0f, 0.0f, 0.0f, 0.0f};
    for (int k = 0; k <= m; ++k) {
        float p = srow[k];                   // wave-uniform broadcast
        float4 vv = vr[(size_t)k * 256 + tid];
        acc.x += p * vv.x; acc.y += p * vv.y;
        acc.z += p * vv.z; acc.w += p * vv.w;
    }
    ((float4*)out)[(size_t)m * 256 + tid] = acc;   // fp32 output
}

extern "C" void kernel_launch(void* const* d_in, const int* in_sizes, int n_in,
                              void* d_out, int out_size, void* d_ws, size_t ws_size,
                              hipStream_t stream) {
    const float* x  = (const float*)d_in[0];   // fp32, per reference dtypes
    const float* wq = (const float*)d_in[1];
    const float* wk = (const float*)d_in[2];
    const float* wv = (const float*)d_in[3];

    const size_t MiB = 1024 * 1024;
    char* ws = (char*)d_ws;
    float* q = (float*)(ws);             //  8 MiB  (2048x1024 f32)
    float* k = (float*)(ws +  8 * MiB);  //  8 MiB
    float* v = (float*)(ws + 16 * MiB);  //  8 MiB
    float* S = (float*)(ws + 24 * MiB);  // 16 MiB  (2048x2048 f32, in-place softmax)
    float* out = (float*)d_out;          // fp32 output; total ws use: 40 MiB

    for (int b = 0; b < 4; ++b) {
        const float* xb = x + (size_t)b * 2048 * 1024;
        float* outb = out + (size_t)b * 2048 * 1024;
        proj_kernel   <<<dim3(4, 2048, 3), 256, 0, stream>>>(xb, wq, wk, wv, q, k, v);
        rope_kernel   <<<dim3(4096),       256, 0, stream>>>(q, k);
        scores_kernel <<<dim3(8, 2048),    256, 0, stream>>>(q, k, S);
        softmax_kernel<<<dim3(2048),       256, 0, stream>>>(S);
        pv_kernel     <<<dim3(2048),       256, 0, stream>>>(S, v, outb);
    }
}

// Round 6
// 466.923 us; speedup vs baseline: 41.5363x; 41.5363x over previous
//
#include <hip/hip_runtime.h>
#include <hip/hip_bf16.h>
#include <math.h>

// MFMA round on the green R5 anchor. All I/O fp32; internally bf16 MFMA.
// Per batch b:
//   cvt x_b -> xb (bf16);  (weights converted once)
//   qkv_rope: 3 NT GEMMs xb[2048x1024] . W[1024x1024]^T via mfma 16x16x32;
//             RoPE fused in epilogue for Q/K; V written transposed VT[1024][2048].
//   scores: NT GEMM Qr.Kr^T (lower tiles only) -> S fp32, scale 1/32.
//   softmax: rows of S -> P bf16 (upper zero-filled).
//   pv: NT GEMM P[2048x2048] . VT[1024x2048]^T -> out fp32.
// MFMA core: 64x64 block tile, 4 waves x (2x2) mfma_f32_16x16x32_bf16.
// Layouts (verified, learn_hip m89/m91): A[m=lane&15][k=quad*8+j],
// B[n=lane&15][k=quad*8+j], C/D col=lane&15, row=quad*4+reg.
// Workspace: 46 MiB (R5 proved >=40 MiB available).

typedef __bf16 bf16x8 __attribute__((ext_vector_type(8)));
typedef float  f32x4  __attribute__((ext_vector_type(4)));

#define LDS_STRIDE 40   // 32 + 8 pad: 16B-aligned rows, 2-way bank alias (free)

__device__ __forceinline__ ushort f2bf(float f) {
    __hip_bfloat16 h = __float2bfloat16(f);
    return *reinterpret_cast<ushort*>(&h);
}

__global__ __launch_bounds__(256) void cvt_kernel(
    const float* __restrict__ in, ushort* __restrict__ out, int n4)
{
    int i = blockIdx.x * blockDim.x + threadIdx.x;
    if (i < n4) {
        float4 f = ((const float4*)in)[i];
        ushort4 o;
        o.x = f2bf(f.x); o.y = f2bf(f.y); o.z = f2bf(f.z); o.w = f2bf(f.w);
        ((ushort4*)out)[i] = o;
    }
}

// NT GEMM core: C[64x64] at (m0,n0) += A[m0..+64][k] * B[n0..+64][k], k=32*kIters.
__device__ __forceinline__ void gemm64_core(
    const ushort* __restrict__ A, const ushort* __restrict__ B,
    int lda, int ldb, int m0, int n0, int kIters,
    ushort* As, ushort* Bs, f32x4 acc[2][2])
{
    const int tid  = threadIdx.x;
    const int lane = tid & 63, wave = tid >> 6;
    const int wm = (wave >> 1) * 32, wn = (wave & 1) * 32;
    const int quad = lane >> 4, l16 = lane & 15;
    const int srow = tid >> 2, scol = (tid & 3) * 8;

    const ushort* ag = A + (size_t)(m0 + srow) * lda + scol;
    const ushort* bg = B + (size_t)(n0 + srow) * ldb + scol;
    ushort* asw = As + srow * LDS_STRIDE + scol;
    ushort* bsw = Bs + srow * LDS_STRIDE + scol;

    for (int kt = 0; kt < kIters; ++kt) {
        int4 av = *(const int4*)ag;   // 8 bf16 = 16 B
        int4 bv = *(const int4*)bg;
        *(int4*)asw = av;
        *(int4*)bsw = bv;
        __syncthreads();
        bf16x8 aF[2], bF[2];
#pragma unroll
        for (int i = 0; i < 2; ++i)
            aF[i] = *(const bf16x8*)(As + (wm + i * 16 + l16) * LDS_STRIDE + quad * 8);
#pragma unroll
        for (int j = 0; j < 2; ++j)
            bF[j] = *(const bf16x8*)(Bs + (wn + j * 16 + l16) * LDS_STRIDE + quad * 8);
#pragma unroll
        for (int i = 0; i < 2; ++i)
#pragma unroll
            for (int j = 0; j < 2; ++j)
                acc[i][j] = __builtin_amdgcn_mfma_f32_16x16x32_bf16(aF[i], bF[j], acc[i][j], 0, 0, 0);
        __syncthreads();
        ag += 32; bg += 32;
    }
}

#define ACC_INIT(acc) \
    _Pragma("unroll") for (int i = 0; i < 2; ++i) \
    _Pragma("unroll") for (int j = 0; j < 2; ++j) \
    _Pragma("unroll") for (int r = 0; r < 4; ++r) acc[i][j][r] = 0.0f;

// Per batch: m0 = bx*64 in [0,2048), n0 = by*64 in [0,1024), z in {Q,K,V}.
__global__ __launch_bounds__(256) void qkv_rope_kernel(
    const ushort* __restrict__ xb, const ushort* __restrict__ wq,
    const ushort* __restrict__ wk, const ushort* __restrict__ wv,
    ushort* __restrict__ Qr, ushort* __restrict__ Kr, ushort* __restrict__ VT)
{
    __shared__ __attribute__((aligned(16))) ushort As[64 * LDS_STRIDE];
    __shared__ __attribute__((aligned(16))) ushort Bs[64 * LDS_STRIDE];
    const int m0 = blockIdx.x * 64;
    const int n0 = blockIdx.y * 64;
    const int z  = blockIdx.z;
    const ushort* W = (z == 0) ? wq : (z == 1) ? wk : wv;

    f32x4 acc[2][2];
    ACC_INIT(acc)
    gemm64_core(xb, W, 1024, 1024, m0, n0, 32, As, Bs, acc);

    const int lane = threadIdx.x & 63, wave = threadIdx.x >> 6;
    const int wm = (wave >> 1) * 32, wn = (wave & 1) * 32;
    const int quad = lane >> 4, l16 = lane & 15;

    if (z < 2) {
        ushort* out = (z == 0) ? Qr : Kr;
#pragma unroll
        for (int i = 0; i < 2; ++i) {
#pragma unroll
            for (int j = 0; j < 2; ++j) {
                const int n = n0 + wn + j * 16 + l16;
                // phi = 10000^(-2*(i_pair-1)/1024), i_pair = n>>1 (ref's -1 quirk)
                const float phi = powf(10000.0f, -2.0f * ((float)(n >> 1) - 1.0f) / 1024.0f);
#pragma unroll
                for (int r = 0; r < 4; ++r) {
                    const int m = m0 + wm + i * 16 + quad * 4 + r;   // pos = m (per batch)
                    float s, c;
                    sincosf((float)m * phi, &s, &c);
                    float v = acc[i][j][r];
                    float p = __shfl_xor(v, 1);   // partner column n^1, same row
                    // even n (te=v, to=p): oe = v*c + p*s ; odd n (te=p, to=v): oo = -p*s + v*c
                    float o = (n & 1) ? (v * c - p * s) : (v * c + p * s);
                    out[(size_t)m * 1024 + n] = f2bf(o);
                }
            }
        }
    } else {
#pragma unroll
        for (int i = 0; i < 2; ++i)
#pragma unroll
            for (int j = 0; j < 2; ++j) {
                const int n = n0 + wn + j * 16 + l16;
#pragma unroll
                for (int r = 0; r < 4; ++r) {
                    const int m = m0 + wm + i * 16 + quad * 4 + r;
                    VT[(size_t)n * 2048 + m] = f2bf(acc[i][j][r]);   // transposed
                }
            }
    }
}

__global__ __launch_bounds__(256) void scores_kernel(
    const ushort* __restrict__ Qr, const ushort* __restrict__ Kr,
    float* __restrict__ S)
{
    const int m0 = blockIdx.x * 64;
    const int n0 = blockIdx.y * 64;
    if (n0 > m0 + 63) return;   // fully above causal diagonal: never read
    __shared__ __attribute__((aligned(16))) ushort As[64 * LDS_STRIDE];
    __shared__ __attribute__((aligned(16))) ushort Bs[64 * LDS_STRIDE];

    f32x4 acc[2][2];
    ACC_INIT(acc)
    gemm64_core(Qr, Kr, 1024, 1024, m0, n0, 32, As, Bs, acc);

    const int lane = threadIdx.x & 63, wave = threadIdx.x >> 6;
    const int wm = (wave >> 1) * 32, wn = (wave & 1) * 32;
    const int quad = lane >> 4, l16 = lane & 15;
#pragma unroll
    for (int i = 0; i < 2; ++i)
#pragma unroll
        for (int j = 0; j < 2; ++j) {
            const int n = n0 + wn + j * 16 + l16;
#pragma unroll
            for (int r = 0; r < 4; ++r) {
                const int m = m0 + wm + i * 16 + quad * 4 + r;
                S[(size_t)m * 2048 + n] = acc[i][j][r] * 0.03125f;   // 1/sqrt(1024)
            }
        }
}

__global__ __launch_bounds__(256) void softmax_kernel(
    const float* __restrict__ S, ushort* __restrict__ P)
{
    __shared__ float red[256];
    const int row = blockIdx.x, tid = threadIdx.x;
    const float* s = S + (size_t)row * 2048;
    ushort*      p = P + (size_t)row * 2048;
    const int n = row + 1;   // valid keys [0, row]

    float mx = -3.402823466e38f;
    for (int j = tid; j < n; j += 256) mx = fmaxf(mx, s[j]);
    red[tid] = mx; __syncthreads();
    for (int off = 128; off > 0; off >>= 1) {
        if (tid < off) red[tid] = fmaxf(red[tid], red[tid + off]);
        __syncthreads();
    }
    mx = red[0]; __syncthreads();

    float sum = 0.0f;
    for (int j = tid; j < n; j += 256) sum += expf(s[j] - mx);
    red[tid] = sum; __syncthreads();
    for (int off = 128; off > 0; off >>= 1) {
        if (tid < off) red[tid] += red[tid + off];
        __syncthreads();
    }
    const float inv = 1.0f / red[0];

    for (int j = tid; j < n; j += 256) p[j] = f2bf(expf(s[j] - mx) * inv);
    for (int j = n + tid; j < 2048; j += 256) p[j] = 0;   // zero above diagonal
}

__global__ __launch_bounds__(256) void pv_kernel(
    const ushort* __restrict__ P, const ushort* __restrict__ VT,
    float* __restrict__ out)
{
    __shared__ __attribute__((aligned(16))) ushort As[64 * LDS_STRIDE];
    __shared__ __attribute__((aligned(16))) ushort Bs[64 * LDS_STRIDE];
    const int m0 = blockIdx.x * 64;
    const int n0 = blockIdx.y * 64;
    const int kIters = (m0 + 64) / 32;   // causal: P[m][k]=0 for k>m

    f32x4 acc[2][2];
    ACC_INIT(acc)
    gemm64_core(P, VT, 2048, 2048, m0, n0, kIters, As, Bs, acc);

    const int lane = threadIdx.x & 63, wave = threadIdx.x >> 6;
    const int wm = (wave >> 1) * 32, wn = (wave & 1) * 32;
    const int quad = lane >> 4, l16 = lane & 15;
#pragma unroll
    for (int i = 0; i < 2; ++i)
#pragma unroll
        for (int j = 0; j < 2; ++j) {
            const int n = n0 + wn + j * 16 + l16;
#pragma unroll
            for (int r = 0; r < 4; ++r) {
                const int m = m0 + wm + i * 16 + quad * 4 + r;
                out[(size_t)m * 1024 + n] = acc[i][j][r];   // fp32 output
            }
        }
}

extern "C" void kernel_launch(void* const* d_in, const int* in_sizes, int n_in,
                              void* d_out, int out_size, void* d_ws, size_t ws_size,
                              hipStream_t stream) {
    const float* x  = (const float*)d_in[0];   // fp32 per reference
    const float* wq = (const float*)d_in[1];
    const float* wk = (const float*)d_in[2];
    const float* wv = (const float*)d_in[3];

    const size_t MiB = 1024 * 1024;
    char* ws = (char*)d_ws;
    ushort* wqb = (ushort*)(ws);             // 2 MiB (1024x1024 bf16)
    ushort* wkb = (ushort*)(ws +  2 * MiB);
    ushort* wvb = (ushort*)(ws +  4 * MiB);
    ushort* xb  = (ushort*)(ws +  6 * MiB);  // 4 MiB (2048x1024 bf16, per batch)
    ushort* Qr  = (ushort*)(ws + 10 * MiB);  // 4 MiB
    ushort* Kr  = (ushort*)(ws + 14 * MiB);  // 4 MiB
    ushort* VT  = (ushort*)(ws + 18 * MiB);  // 4 MiB (1024x2048 bf16)
    float*  S   = (float* )(ws + 22 * MiB);  // 16 MiB (2048x2048 f32)
    ushort* P   = (ushort*)(ws + 38 * MiB);  // 8 MiB (2048x2048 bf16)
    float*  out = (float*)d_out;             // total ws: 46 MiB

    cvt_kernel<<<dim3(1024), 256, 0, stream>>>(wq, wqb, 262144);
    cvt_kernel<<<dim3(1024), 256, 0, stream>>>(wk, wkb, 262144);
    cvt_kernel<<<dim3(1024), 256, 0, stream>>>(wv, wvb, 262144);

    for (int b = 0; b < 4; ++b) {
        const float* xf = x + (size_t)b * 2048 * 1024;
        float* outb = out + (size_t)b * 2048 * 1024;
        cvt_kernel     <<<dim3(2048),        256, 0, stream>>>(xf, xb, 524288);
        qkv_rope_kernel<<<dim3(32, 16, 3),   256, 0, stream>>>(xb, wqb, wkb, wvb, Qr, Kr, VT);
        scores_kernel  <<<dim3(32, 32),      256, 0, stream>>>(Qr, Kr, S);
        softmax_kernel <<<dim3(2048),        256, 0, stream>>>(S, P);
        pv_kernel      <<<dim3(32, 16),      256, 0, stream>>>(P, VT, outb);
    }
}

// Round 7
// 390.973 us; speedup vs baseline: 49.6051x; 1.1943x over previous
//
#include <hip/hip_runtime.h>
#include <hip/hip_bf16.h>
#include <math.h>

// Batched round: all batches in single launches (grid.z), cvt of x fused into
// QKV staging. ws_size measured at 256 MiB (poison fills = 2.685e8 B), so the
// full-batch intermediate set (144 MiB) fits.
//   cvt: weights fp32->bf16 (once, 3 launches).
//   qkv_rope: grid(128,16,3) over all 8192 rows; A-side reads x fp32 and
//             converts in-register; RoPE epilogue for Q/K (pos = m&2047);
//             V written transposed VT[b][d][m].
//   scores: grid(32,32,4), lower tiles only -> S fp32 (scale 1/32).
//   softmax: grid(2048,4), register-staged row -> P bf16 (upper zeroed).
//   pv: grid(32,16,4), causal k-limit -> out fp32.
// MFMA core: 64x64 tile, 4 waves x (2x2) mfma_f32_16x16x32_bf16 (verified
// layouts m89/m91). LDS stride 40 (2-way bank alias = free).

typedef __bf16 bf16x8 __attribute__((ext_vector_type(8)));
typedef float  f32x4  __attribute__((ext_vector_type(4)));

#define LDS_STRIDE 40

__device__ __forceinline__ ushort f2bf(float f) {
    __hip_bfloat16 h = __float2bfloat16(f);
    return *reinterpret_cast<ushort*>(&h);
}

__global__ __launch_bounds__(256) void cvt_kernel(
    const float* __restrict__ in, ushort* __restrict__ out, int n4)
{
    int i = blockIdx.x * blockDim.x + threadIdx.x;
    if (i < n4) {
        float4 f = ((const float4*)in)[i];
        ushort4 o;
        o.x = f2bf(f.x); o.y = f2bf(f.y); o.z = f2bf(f.z); o.w = f2bf(f.w);
        ((ushort4*)out)[i] = o;
    }
}

// bf16/bf16 NT GEMM core (scores, pv).
__device__ __forceinline__ void gemm64_core(
    const ushort* __restrict__ A, const ushort* __restrict__ B,
    int lda, int ldb, int m0, int n0, int kIters,
    ushort* As, ushort* Bs, f32x4 acc[2][2])
{
    const int tid  = threadIdx.x;
    const int lane = tid & 63, wave = tid >> 6;
    const int wm = (wave >> 1) * 32, wn = (wave & 1) * 32;
    const int quad = lane >> 4, l16 = lane & 15;
    const int srow = tid >> 2, scol = (tid & 3) * 8;

    const ushort* ag = A + (size_t)(m0 + srow) * lda + scol;
    const ushort* bg = B + (size_t)(n0 + srow) * ldb + scol;
    ushort* asw = As + srow * LDS_STRIDE + scol;
    ushort* bsw = Bs + srow * LDS_STRIDE + scol;

    for (int kt = 0; kt < kIters; ++kt) {
        int4 av = *(const int4*)ag;
        int4 bv = *(const int4*)bg;
        *(int4*)asw = av;
        *(int4*)bsw = bv;
        __syncthreads();
        bf16x8 aF[2], bF[2];
#pragma unroll
        for (int i = 0; i < 2; ++i)
            aF[i] = *(const bf16x8*)(As + (wm + i * 16 + l16) * LDS_STRIDE + quad * 8);
#pragma unroll
        for (int j = 0; j < 2; ++j)
            bF[j] = *(const bf16x8*)(Bs + (wn + j * 16 + l16) * LDS_STRIDE + quad * 8);
#pragma unroll
        for (int i = 0; i < 2; ++i)
#pragma unroll
            for (int j = 0; j < 2; ++j)
                acc[i][j] = __builtin_amdgcn_mfma_f32_16x16x32_bf16(aF[i], bF[j], acc[i][j], 0, 0, 0);
        __syncthreads();
        ag += 32; bg += 32;
    }
}

#define ACC_INIT(acc) \
    _Pragma("unroll") for (int i = 0; i < 2; ++i) \
    _Pragma("unroll") for (int j = 0; j < 2; ++j) \
    _Pragma("unroll") for (int r = 0; r < 4; ++r) acc[i][j][r] = 0.0f;

// QKV: A = x fp32 (converted in staging), B = weights bf16. All 8192 rows.
__global__ __launch_bounds__(256) void qkv_rope_kernel(
    const float* __restrict__ x, const ushort* __restrict__ wq,
    const ushort* __restrict__ wk, const ushort* __restrict__ wv,
    ushort* __restrict__ Qr, ushort* __restrict__ Kr, ushort* __restrict__ VT)
{
    __shared__ __attribute__((aligned(16))) ushort As[64 * LDS_STRIDE];
    __shared__ __attribute__((aligned(16))) ushort Bs[64 * LDS_STRIDE];
    const int m0 = blockIdx.x * 64;   // global row in [0, 8192)
    const int n0 = blockIdx.y * 64;   // feature col in [0, 1024)
    const int z  = blockIdx.z;
    const ushort* W = (z == 0) ? wq : (z == 1) ? wk : wv;

    const int tid  = threadIdx.x;
    const int lane = tid & 63, wave = tid >> 6;
    const int wm = (wave >> 1) * 32, wn = (wave & 1) * 32;
    const int quad = lane >> 4, l16 = lane & 15;
    const int srow = tid >> 2, scol = (tid & 3) * 8;

    const float*  ag = x + (size_t)(m0 + srow) * 1024 + scol;
    const ushort* bg = W + (size_t)(n0 + srow) * 1024 + scol;
    ushort* asw = As + srow * LDS_STRIDE + scol;
    ushort* bsw = Bs + srow * LDS_STRIDE + scol;

    f32x4 acc[2][2];
    ACC_INIT(acc)

    for (int kt = 0; kt < 32; ++kt) {
        float4 a0 = *(const float4*)ag;
        float4 a1 = *(const float4*)(ag + 4);
        int4 bv = *(const int4*)bg;
        ushort as8[8];
        as8[0] = f2bf(a0.x); as8[1] = f2bf(a0.y); as8[2] = f2bf(a0.z); as8[3] = f2bf(a0.w);
        as8[4] = f2bf(a1.x); as8[5] = f2bf(a1.y); as8[6] = f2bf(a1.z); as8[7] = f2bf(a1.w);
        *(int4*)asw = *(const int4*)as8;
        *(int4*)bsw = bv;
        __syncthreads();
        bf16x8 aF[2], bF[2];
#pragma unroll
        for (int i = 0; i < 2; ++i)
            aF[i] = *(const bf16x8*)(As + (wm + i * 16 + l16) * LDS_STRIDE + quad * 8);
#pragma unroll
        for (int j = 0; j < 2; ++j)
            bF[j] = *(const bf16x8*)(Bs + (wn + j * 16 + l16) * LDS_STRIDE + quad * 8);
#pragma unroll
        for (int i = 0; i < 2; ++i)
#pragma unroll
            for (int j = 0; j < 2; ++j)
                acc[i][j] = __builtin_amdgcn_mfma_f32_16x16x32_bf16(aF[i], bF[j], acc[i][j], 0, 0, 0);
        __syncthreads();
        ag += 32; bg += 32;
    }

    if (z < 2) {
        ushort* out = (z == 0) ? Qr : Kr;
#pragma unroll
        for (int i = 0; i < 2; ++i) {
#pragma unroll
            for (int j = 0; j < 2; ++j) {
                const int n = n0 + wn + j * 16 + l16;
                // phi = 10000^(-2*(pair-1)/1024), pair = n>>1 (reference's -1 quirk)
                const float phi = powf(10000.0f, -2.0f * ((float)(n >> 1) - 1.0f) / 1024.0f);
#pragma unroll
                for (int r = 0; r < 4; ++r) {
                    const int m = m0 + wm + i * 16 + quad * 4 + r;
                    const int pos = m & 2047;
                    float s, c;
                    sincosf((float)pos * phi, &s, &c);
                    float v = acc[i][j][r];
                    float p = __shfl_xor(v, 1);   // partner column n^1, same row
                    float o = (n & 1) ? (v * c - p * s) : (v * c + p * s);
                    out[(size_t)m * 1024 + n] = f2bf(o);
                }
            }
        }
    } else {
#pragma unroll
        for (int i = 0; i < 2; ++i)
#pragma unroll
            for (int j = 0; j < 2; ++j) {
                const int n = n0 + wn + j * 16 + l16;
#pragma unroll
                for (int r = 0; r < 4; ++r) {
                    const int m = m0 + wm + i * 16 + quad * 4 + r;
                    const int b = m >> 11, pos = m & 2047;
                    VT[((size_t)b * 1024 + n) * 2048 + pos] = f2bf(acc[i][j][r]);
                }
            }
    }
}

__global__ __launch_bounds__(256) void scores_kernel(
    const ushort* __restrict__ Qr, const ushort* __restrict__ Kr,
    float* __restrict__ S)
{
    const int m0 = blockIdx.x * 64;
    const int n0 = blockIdx.y * 64;
    if (n0 > m0 + 63) return;   // fully above causal diagonal
    const int b = blockIdx.z;
    __shared__ __attribute__((aligned(16))) ushort As[64 * LDS_STRIDE];
    __shared__ __attribute__((aligned(16))) ushort Bs[64 * LDS_STRIDE];
    const ushort* A = Qr + (size_t)b * 2048 * 1024;
    const ushort* B = Kr + (size_t)b * 2048 * 1024;
    float* Sb = S + (size_t)b * 2048 * 2048;

    f32x4 acc[2][2];
    ACC_INIT(acc)
    gemm64_core(A, B, 1024, 1024, m0, n0, 32, As, Bs, acc);

    const int lane = threadIdx.x & 63, wave = threadIdx.x >> 6;
    const int wm = (wave >> 1) * 32, wn = (wave & 1) * 32;
    const int quad = lane >> 4, l16 = lane & 15;
#pragma unroll
    for (int i = 0; i < 2; ++i)
#pragma unroll
        for (int j = 0; j < 2; ++j) {
            const int n = n0 + wn + j * 16 + l16;
#pragma unroll
            for (int r = 0; r < 4; ++r) {
                const int m = m0 + wm + i * 16 + quad * 4 + r;
                Sb[(size_t)m * 2048 + n] = acc[i][j][r] * 0.03125f;
            }
        }
}

// Row softmax, register-staged: 8 elems/thread, one int4 bf16 write.
__global__ __launch_bounds__(256) void softmax_kernel(
    const float* __restrict__ S, ushort* __restrict__ P)
{
    __shared__ float red[256];
    const int row = blockIdx.x, tid = threadIdx.x, b = blockIdx.y;
    const float* s = S + ((size_t)b * 2048 + row) * 2048;
    ushort*      p = P + ((size_t)b * 2048 + row) * 2048;
    const int nvalid = row + 1;
    const int j0 = tid * 8;

    float v[8];
    float4 f0 = *(const float4*)(s + j0);
    float4 f1 = *(const float4*)(s + j0 + 4);
    v[0]=f0.x; v[1]=f0.y; v[2]=f0.z; v[3]=f0.w;
    v[4]=f1.x; v[5]=f1.y; v[6]=f1.z; v[7]=f1.w;

    float mx = -3.402823466e38f;
#pragma unroll
    for (int u = 0; u < 8; ++u) if (j0 + u < nvalid) mx = fmaxf(mx, v[u]);
    red[tid] = mx; __syncthreads();
    for (int off = 128; off > 0; off >>= 1) {
        if (tid < off) red[tid] = fmaxf(red[tid], red[tid + off]);
        __syncthreads();
    }
    mx = red[0]; __syncthreads();

    float sum = 0.0f;
#pragma unroll
    for (int u = 0; u < 8; ++u) {
        v[u] = (j0 + u < nvalid) ? __expf(v[u] - mx) : 0.0f;
        sum += v[u];
    }
    red[tid] = sum; __syncthreads();
    for (int off = 128; off > 0; off >>= 1) {
        if (tid < off) red[tid] += red[tid + off];
        __syncthreads();
    }
    const float inv = 1.0f / red[0];

    ushort o[8];
#pragma unroll
    for (int u = 0; u < 8; ++u) o[u] = f2bf(v[u] * inv);
    *(int4*)(p + j0) = *(const int4*)o;
}

__global__ __launch_bounds__(256) void pv_kernel(
    const ushort* __restrict__ P, const ushort* __restrict__ VT,
    float* __restrict__ out)
{
    __shared__ __attribute__((aligned(16))) ushort As[64 * LDS_STRIDE];
    __shared__ __attribute__((aligned(16))) ushort Bs[64 * LDS_STRIDE];
    const int m0 = blockIdx.x * 64;
    const int n0 = blockIdx.y * 64;
    const int b  = blockIdx.z;
    const ushort* A = P + (size_t)b * 2048 * 2048;
    const ushort* B = VT + (size_t)b * 1024 * 2048;
    const int kIters = (m0 + 64) / 32;   // causal: P[m][k]=0 for k>m

    f32x4 acc[2][2];
    ACC_INIT(acc)
    gemm64_core(A, B, 2048, 2048, m0, n0, kIters, As, Bs, acc);

    const int lane = threadIdx.x & 63, wave = threadIdx.x >> 6;
    const int wm = (wave >> 1) * 32, wn = (wave & 1) * 32;
    const int quad = lane >> 4, l16 = lane & 15;
#pragma unroll
    for (int i = 0; i < 2; ++i)
#pragma unroll
        for (int j = 0; j < 2; ++j) {
            const int n = n0 + wn + j * 16 + l16;
#pragma unroll
            for (int r = 0; r < 4; ++r) {
                const int m = m0 + wm + i * 16 + quad * 4 + r;
                out[((size_t)b * 2048 + m) * 1024 + n] = acc[i][j][r];
            }
        }
}

extern "C" void kernel_launch(void* const* d_in, const int* in_sizes, int n_in,
                              void* d_out, int out_size, void* d_ws, size_t ws_size,
                              hipStream_t stream) {
    const float* x  = (const float*)d_in[0];
    const float* wq = (const float*)d_in[1];
    const float* wk = (const float*)d_in[2];
    const float* wv = (const float*)d_in[3];

    const size_t MiB = 1024 * 1024;
    char* ws = (char*)d_ws;
    ushort* wqb = (ushort*)(ws);              //   2 MiB
    ushort* wkb = (ushort*)(ws +   2 * MiB);  //   2 MiB
    ushort* wvb = (ushort*)(ws +   4 * MiB);  //   2 MiB
    ushort* Qr  = (ushort*)(ws +   6 * MiB);  //  16 MiB [4][2048][1024] bf16
    ushort* Kr  = (ushort*)(ws +  22 * MiB);  //  16 MiB
    ushort* VT  = (ushort*)(ws +  38 * MiB);  //  16 MiB [4][1024][2048] bf16
    float*  S   = (float* )(ws +  54 * MiB);  //  64 MiB [4][2048][2048] f32
    ushort* P   = (ushort*)(ws + 118 * MiB);  //  32 MiB [4][2048][2048] bf16
    float*  out = (float*)d_out;              // total ws: 150 MiB (256 MiB avail)

    cvt_kernel<<<dim3(1024), 256, 0, stream>>>(wq, wqb, 262144);
    cvt_kernel<<<dim3(1024), 256, 0, stream>>>(wk, wkb, 262144);
    cvt_kernel<<<dim3(1024), 256, 0, stream>>>(wv, wvb, 262144);

    qkv_rope_kernel<<<dim3(128, 16, 3), 256, 0, stream>>>(x, wqb, wkb, wvb, Qr, Kr, VT);
    scores_kernel  <<<dim3(32, 32, 4),  256, 0, stream>>>(Qr, Kr, S);
    softmax_kernel <<<dim3(2048, 4),    256, 0, stream>>>(S, P);
    pv_kernel      <<<dim3(32, 16, 4),  256, 0, stream>>>(P, VT, out);
}

// Round 8
// 305.077 us; speedup vs baseline: 63.5718x; 1.2816x over previous
//
#include <hip/hip_runtime.h>
#include <hip/hip_bf16.h>
#include <math.h>

// m97-structure round: all GEMMs upgraded to 128x128 tile, BK=32, 4 waves in
// 2x2 grid (64x64 per wave = 4x4 mfma_f32_16x16x32_bf16), staging via
// __builtin_amdgcn_global_load_lds width=16 into CONTIGUOUS LDS [128][32]
// (no padding - required by wave-uniform-base+lane*16 DMA semantics).
// Pipeline: cvt x+w -> bf16; qkv_rope (RoPE epilogue w/ rotation recurrence,
// V written transposed via ushort4); scores (causal-skipped, fp32 S);
// softmax (register-staged) -> P bf16; pv (causal k-limit) -> out fp32.
// ws measured 256 MiB (R6 poison fills); usage here 166 MiB.

typedef __bf16 bf16x8 __attribute__((ext_vector_type(8)));
typedef float  f32x4  __attribute__((ext_vector_type(4)));

__device__ __forceinline__ ushort f2bf(float f) {
    __hip_bfloat16 h = __float2bfloat16(f);
    return *reinterpret_cast<ushort*>(&h);
}

__device__ __forceinline__ void async_load16(const ushort* g, ushort* l) {
    __builtin_amdgcn_global_load_lds(
        (const __attribute__((address_space(1))) void*)g,
        (__attribute__((address_space(3))) void*)l, 16, 0, 0);
}

__global__ __launch_bounds__(256) void cvt_kernel(
    const float* __restrict__ in, ushort* __restrict__ out, int n4)
{
    int i = blockIdx.x * blockDim.x + threadIdx.x;
    if (i < n4) {
        float4 f = ((const float4*)in)[i];
        ushort4 o;
        o.x = f2bf(f.x); o.y = f2bf(f.y); o.z = f2bf(f.z); o.w = f2bf(f.w);
        ((ushort4*)out)[i] = o;
    }
}

// NT GEMM core, 128x128 tile: C at (m0,n0) += A[m0..+128][k] * B[n0..+128][k],
// k = 32*kIters. As/Bs: contiguous [128][32] bf16 (8 KB each).
// Wave w stages rows [w*32, w*32+32) of both tiles: 2 global_load_lds x16B per
// operand per wave (lane -> row w*32+t*16+(lane>>2), kchunk (lane&3)*8).
__device__ __forceinline__ void gemm128_core(
    const ushort* __restrict__ A, const ushort* __restrict__ B,
    int lda, int ldb, int m0, int n0, int kIters,
    ushort* As, ushort* Bs, f32x4 acc[4][4])
{
    const int tid  = threadIdx.x;
    const int lane = tid & 63, wave = tid >> 6;
    const int wm = (wave >> 1) * 64, wn = (wave & 1) * 64;
    const int quad = lane >> 4, l16 = lane & 15;
    const int srow = lane >> 2, scol = (lane & 3) * 8;

    const ushort* ag0 = A + (size_t)(m0 + wave * 32 + srow) * lda + scol;
    const ushort* bg0 = B + (size_t)(n0 + wave * 32 + srow) * ldb + scol;
    const ushort* ag1 = ag0 + (size_t)16 * lda;
    const ushort* bg1 = bg0 + (size_t)16 * ldb;
    ushort* la0 = As + (wave * 32) * 32;
    ushort* la1 = As + (wave * 32 + 16) * 32;
    ushort* lb0 = Bs + (wave * 32) * 32;
    ushort* lb1 = Bs + (wave * 32 + 16) * 32;

    for (int kt = 0; kt < kIters; ++kt) {
        const int k0 = kt * 32;
        async_load16(ag0 + k0, la0);
        async_load16(ag1 + k0, la1);
        async_load16(bg0 + k0, lb0);
        async_load16(bg1 + k0, lb1);
        __syncthreads();   // drains vmcnt -> LDS tiles ready
        bf16x8 aF[4], bF[4];
#pragma unroll
        for (int i = 0; i < 4; ++i)
            aF[i] = *(const bf16x8*)(As + (wm + i * 16 + l16) * 32 + quad * 8);
#pragma unroll
        for (int j = 0; j < 4; ++j)
            bF[j] = *(const bf16x8*)(Bs + (wn + j * 16 + l16) * 32 + quad * 8);
#pragma unroll
        for (int i = 0; i < 4; ++i)
#pragma unroll
            for (int j = 0; j < 4; ++j)
                acc[i][j] = __builtin_amdgcn_mfma_f32_16x16x32_bf16(aF[i], bF[j], acc[i][j], 0, 0, 0);
        __syncthreads();   // all waves done reading before next overwrite
    }
}

#define ACC_INIT(acc) \
    _Pragma("unroll") for (int i = 0; i < 4; ++i) \
    _Pragma("unroll") for (int j = 0; j < 4; ++j) \
    _Pragma("unroll") for (int r = 0; r < 4; ++r) acc[i][j][r] = 0.0f;

// QKV + RoPE. grid (64, 8, 3): m0 = bx*128 in [0,8192), n0 = by*128, z=Q/K/V.
__global__ __launch_bounds__(256) void qkv_rope_kernel(
    const ushort* __restrict__ xb, const ushort* __restrict__ wq,
    const ushort* __restrict__ wk, const ushort* __restrict__ wv,
    ushort* __restrict__ Qr, ushort* __restrict__ Kr, ushort* __restrict__ VT)
{
    __shared__ __attribute__((aligned(16))) ushort As[128 * 32];
    __shared__ __attribute__((aligned(16))) ushort Bs[128 * 32];
    const int m0 = blockIdx.x * 128;
    const int n0 = blockIdx.y * 128;
    const int z  = blockIdx.z;
    const ushort* W = (z == 0) ? wq : (z == 1) ? wk : wv;

    f32x4 acc[4][4];
    ACC_INIT(acc)
    gemm128_core(xb, W, 1024, 1024, m0, n0, 32, As, Bs, acc);

    const int lane = threadIdx.x & 63, wave = threadIdx.x >> 6;
    const int wm = (wave >> 1) * 64, wn = (wave & 1) * 64;
    const int quad = lane >> 4, l16 = lane & 15;

    if (z < 2) {
        ushort* out = (z == 0) ? Qr : Kr;
#pragma unroll
        for (int j = 0; j < 4; ++j) {
            const int n = n0 + wn + j * 16 + l16;
            // phi = 10000^(-2*(pair-1)/1024), pair = n>>1 (reference's -1 quirk)
            const float phi = powf(10000.0f, -2.0f * ((float)(n >> 1) - 1.0f) / 1024.0f);
            float sphi, cphi;
            sincosf(phi, &sphi, &cphi);          // rotation step for pos+1
#pragma unroll
            for (int i = 0; i < 4; ++i) {
                const int mbase = m0 + wm + i * 16 + quad * 4;
                const int pos0  = mbase & 2047;
                float s, c;
                sincosf((float)pos0 * phi, &s, &c);
#pragma unroll
                for (int r = 0; r < 4; ++r) {
                    float v = acc[i][j][r];
                    float p = __shfl_xor(v, 1);   // partner column n^1, same row
                    float o = (n & 1) ? (v * c - p * s) : (v * c + p * s);
                    out[(size_t)(mbase + r) * 1024 + n] = f2bf(o);
                    float s2 = s * cphi + c * sphi;   // rotate to pos+1
                    c = c * cphi - s * sphi;
                    s = s2;
                }
            }
        }
    } else {
        // V transposed: VT[b][n][pos]; 4 consecutive pos per (quad) -> ushort4
#pragma unroll
        for (int i = 0; i < 4; ++i) {
            const int mbase = m0 + wm + i * 16 + quad * 4;
            const int b = mbase >> 11, pos0 = mbase & 2047;
#pragma unroll
            for (int j = 0; j < 4; ++j) {
                const int n = n0 + wn + j * 16 + l16;
                ushort4 o;
                o.x = f2bf(acc[i][j][0]); o.y = f2bf(acc[i][j][1]);
                o.z = f2bf(acc[i][j][2]); o.w = f2bf(acc[i][j][3]);
                *(ushort4*)(VT + ((size_t)b * 1024 + n) * 2048 + pos0) = o;
            }
        }
    }
}

// scores: grid (16, 16, 4); lower tiles only; S fp32 scaled 1/32.
__global__ __launch_bounds__(256) void scores_kernel(
    const ushort* __restrict__ Qr, const ushort* __restrict__ Kr,
    float* __restrict__ S)
{
    const int m0 = blockIdx.x * 128;
    const int n0 = blockIdx.y * 128;
    if (n0 > m0 + 127) return;   // fully above causal diagonal: never read
    const int b = blockIdx.z;
    __shared__ __attribute__((aligned(16))) ushort As[128 * 32];
    __shared__ __attribute__((aligned(16))) ushort Bs[128 * 32];
    const ushort* A = Qr + (size_t)b * 2048 * 1024;
    const ushort* B = Kr + (size_t)b * 2048 * 1024;
    float* Sb = S + (size_t)b * 2048 * 2048;

    f32x4 acc[4][4];
    ACC_INIT(acc)
    gemm128_core(A, B, 1024, 1024, m0, n0, 32, As, Bs, acc);

    const int lane = threadIdx.x & 63, wave = threadIdx.x >> 6;
    const int wm = (wave >> 1) * 64, wn = (wave & 1) * 64;
    const int quad = lane >> 4, l16 = lane & 15;
#pragma unroll
    for (int i = 0; i < 4; ++i)
#pragma unroll
        for (int j = 0; j < 4; ++j) {
            const int n = n0 + wn + j * 16 + l16;
#pragma unroll
            for (int r = 0; r < 4; ++r) {
                const int m = m0 + wm + i * 16 + quad * 4 + r;
                Sb[(size_t)m * 2048 + n] = acc[i][j][r] * 0.03125f;
            }
        }
}

// Row softmax, register-staged: 8 elems/thread, one int4 bf16 write.
__global__ __launch_bounds__(256) void softmax_kernel(
    const float* __restrict__ S, ushort* __restrict__ P)
{
    __shared__ float red[256];
    const int row = blockIdx.x, tid = threadIdx.x, b = blockIdx.y;
    const float* s = S + ((size_t)b * 2048 + row) * 2048;
    ushort*      p = P + ((size_t)b * 2048 + row) * 2048;
    const int nvalid = row + 1;
    const int j0 = tid * 8;

    float v[8];
    float4 f0 = *(const float4*)(s + j0);
    float4 f1 = *(const float4*)(s + j0 + 4);
    v[0]=f0.x; v[1]=f0.y; v[2]=f0.z; v[3]=f0.w;
    v[4]=f1.x; v[5]=f1.y; v[6]=f1.z; v[7]=f1.w;

    float mx = -3.402823466e38f;
#pragma unroll
    for (int u = 0; u < 8; ++u) if (j0 + u < nvalid) mx = fmaxf(mx, v[u]);
    red[tid] = mx; __syncthreads();
    for (int off = 128; off > 0; off >>= 1) {
        if (tid < off) red[tid] = fmaxf(red[tid], red[tid + off]);
        __syncthreads();
    }
    mx = red[0]; __syncthreads();

    float sum = 0.0f;
#pragma unroll
    for (int u = 0; u < 8; ++u) {
        v[u] = (j0 + u < nvalid) ? __expf(v[u] - mx) : 0.0f;
        sum += v[u];
    }
    red[tid] = sum; __syncthreads();
    for (int off = 128; off > 0; off >>= 1) {
        if (tid < off) red[tid] += red[tid + off];
        __syncthreads();
    }
    const float inv = 1.0f / red[0];

    ushort o[8];
#pragma unroll
    for (int u = 0; u < 8; ++u) o[u] = f2bf(v[u] * inv);
    *(int4*)(p + j0) = *(const int4*)o;
}

// pv: grid (16, 8, 4); causal k-limit.
__global__ __launch_bounds__(256) void pv_kernel(
    const ushort* __restrict__ P, const ushort* __restrict__ VT,
    float* __restrict__ out)
{
    __shared__ __attribute__((aligned(16))) ushort As[128 * 32];
    __shared__ __attribute__((aligned(16))) ushort Bs[128 * 32];
    const int m0 = blockIdx.x * 128;
    const int n0 = blockIdx.y * 128;
    const int b  = blockIdx.z;
    const ushort* A = P + (size_t)b * 2048 * 2048;
    const ushort* B = VT + (size_t)b * 1024 * 2048;
    const int kIters = (m0 + 128) / 32;   // causal: P[m][k]=0 for k>m

    f32x4 acc[4][4];
    ACC_INIT(acc)
    gemm128_core(A, B, 2048, 2048, m0, n0, kIters, As, Bs, acc);

    const int lane = threadIdx.x & 63, wave = threadIdx.x >> 6;
    const int wm = (wave >> 1) * 64, wn = (wave & 1) * 64;
    const int quad = lane >> 4, l16 = lane & 15;
#pragma unroll
    for (int i = 0; i < 4; ++i)
#pragma unroll
        for (int j = 0; j < 4; ++j) {
            const int n = n0 + wn + j * 16 + l16;
#pragma unroll
            for (int r = 0; r < 4; ++r) {
                const int m = m0 + wm + i * 16 + quad * 4 + r;
                out[((size_t)b * 2048 + m) * 1024 + n] = acc[i][j][r];
            }
        }
}

extern "C" void kernel_launch(void* const* d_in, const int* in_sizes, int n_in,
                              void* d_out, int out_size, void* d_ws, size_t ws_size,
                              hipStream_t stream) {
    const float* x  = (const float*)d_in[0];
    const float* wq = (const float*)d_in[1];
    const float* wk = (const float*)d_in[2];
    const float* wv = (const float*)d_in[3];

    const size_t MiB = 1024 * 1024;
    char* ws = (char*)d_ws;
    ushort* xb  = (ushort*)(ws);              //  16 MiB [8192][1024] bf16
    ushort* wqb = (ushort*)(ws +  16 * MiB);  //   2 MiB
    ushort* wkb = (ushort*)(ws +  18 * MiB);  //   2 MiB
    ushort* wvb = (ushort*)(ws +  20 * MiB);  //   2 MiB
    ushort* Qr  = (ushort*)(ws +  22 * MiB);  //  16 MiB [4][2048][1024] bf16
    ushort* Kr  = (ushort*)(ws +  38 * MiB);  //  16 MiB
    ushort* VT  = (ushort*)(ws +  54 * MiB);  //  16 MiB [4][1024][2048] bf16
    float*  S   = (float* )(ws +  70 * MiB);  //  64 MiB [4][2048][2048] f32
    ushort* P   = (ushort*)(ws + 134 * MiB);  //  32 MiB [4][2048][2048] bf16
    float*  out = (float*)d_out;              // ws use: 166 MiB (256 avail)

    cvt_kernel<<<dim3(8192), 256, 0, stream>>>(x,  xb,  2097152);
    cvt_kernel<<<dim3(1024), 256, 0, stream>>>(wq, wqb, 262144);
    cvt_kernel<<<dim3(1024), 256, 0, stream>>>(wk, wkb, 262144);
    cvt_kernel<<<dim3(1024), 256, 0, stream>>>(wv, wvb, 262144);

    qkv_rope_kernel<<<dim3(64, 8, 3),  256, 0, stream>>>(xb, wqb, wkb, wvb, Qr, Kr, VT);
    scores_kernel  <<<dim3(16, 16, 4), 256, 0, stream>>>(Qr, Kr, S);
    softmax_kernel <<<dim3(2048, 4),   256, 0, stream>>>(S, P);
    pv_kernel      <<<dim3(16, 8, 4),  256, 0, stream>>>(P, VT, out);
}